// Round 1
// baseline (1649.276 us; speedup 1.0000x reference)
//
#include <hip/hip_runtime.h>

#define N_NEURONS   100000
#define INPUT_SIZE  1024
#define OUTPUT_SIZE 256
#define E_SYN       10000000
#define STEPS       3

// v[i] = x[i] for inputs else 0; nxt pre-seeded with biases (added post-scatter in ref)
__global__ void init_state(const float* __restrict__ x,
                           const float* __restrict__ bias,
                           float* __restrict__ v,
                           float* __restrict__ nxt) {
    int i = blockIdx.x * blockDim.x + threadIdx.x;
    if (i < N_NEURONS) {
        v[i]   = (i < INPUT_SIZE) ? x[i] : 0.0f;
        nxt[i] = (i >= INPUT_SIZE) ? bias[i - INPUT_SIZE] : 0.0f;
    }
}

// 4 edges per thread: vectorized streaming loads of w/src/dst, gather v, atomic scatter
__global__ void scatter_edges(const float* __restrict__ w,
                              const int*   __restrict__ src,
                              const int*   __restrict__ dst,
                              const float* __restrict__ v,
                              float*       __restrict__ nxt) {
    int t = blockIdx.x * blockDim.x + threadIdx.x;
    long base = (long)t * 4;
    if (base + 3 < E_SYN) {
        const int4   s4 = ((const int4*)src)[t];
        const int4   d4 = ((const int4*)dst)[t];
        const float4 w4 = ((const float4*)w)[t];
        float m0 = v[s4.x] * w4.x;
        float m1 = v[s4.y] * w4.y;
        float m2 = v[s4.z] * w4.z;
        float m3 = v[s4.w] * w4.w;
        atomicAdd(&nxt[d4.x], m0);
        atomicAdd(&nxt[d4.y], m1);
        atomicAdd(&nxt[d4.z], m2);
        atomicAdd(&nxt[d4.w], m3);
    } else if (base < E_SYN) {
        for (long e = base; e < E_SYN; ++e)
            atomicAdd(&nxt[dst[e]], v[src[e]] * w[e]);
    }
}

// v = tanh(nxt) except output window; re-seed nxt with biases; emit output on last step
__global__ void update_state(const float* __restrict__ bias,
                             float* __restrict__ v,
                             float* __restrict__ nxt,
                             float* __restrict__ out,
                             int write_out) {
    int i = blockIdx.x * blockDim.x + threadIdx.x;
    if (i < N_NEURONS) {
        float val  = nxt[i];
        float newv = (i < N_NEURONS - OUTPUT_SIZE) ? tanhf(val) : val;
        v[i]   = newv;
        nxt[i] = (i >= INPUT_SIZE) ? bias[i - INPUT_SIZE] : 0.0f;
        if (write_out && i >= N_NEURONS - OUTPUT_SIZE)
            out[i - (N_NEURONS - OUTPUT_SIZE)] = val;
    }
}

extern "C" void kernel_launch(void* const* d_in, const int* in_sizes, int n_in,
                              void* d_out, int out_size, void* d_ws, size_t ws_size,
                              hipStream_t stream) {
    const float* x    = (const float*)d_in[0];
    const float* w    = (const float*)d_in[1];
    const float* bias = (const float*)d_in[2];
    const int*   src  = (const int*)d_in[3];
    const int*   dst  = (const int*)d_in[4];
    float* out = (float*)d_out;

    float* v   = (float*)d_ws;
    float* nxt = v + N_NEURONS;

    const int blk = 256;
    const int grid_n = (N_NEURONS + blk - 1) / blk;
    const int n_thr_e = (E_SYN + 3) / 4;
    const int grid_e = (n_thr_e + blk - 1) / blk;

    init_state<<<grid_n, blk, 0, stream>>>(x, bias, v, nxt);
    for (int s = 0; s < STEPS; ++s) {
        scatter_edges<<<grid_e, blk, 0, stream>>>(w, src, dst, v, nxt);
        update_state<<<grid_n, blk, 0, stream>>>(bias, v, nxt, out, s == STEPS - 1 ? 1 : 0);
    }
}

// Round 2
// 490.303 us; speedup vs baseline: 3.3638x; 3.3638x over previous
//
#include <hip/hip_runtime.h>

#define N_NEURONS   100000
#define INPUT_SIZE  1024
#define OUTPUT_SIZE 256
#define E_SYN       10000000
#define STEPS       3

#define RANGES      8
#define BIN         12500          // neurons per range; RANGES*BIN == N_NEURONS
#define SCAT_BLK    512
#define VEC4        (E_SYN / 4)    // 2,500,000 — E divisible by 4, no tail

// v[i] = x[i] for inputs else 0
__global__ void init_state(const float* __restrict__ x, float* __restrict__ v) {
    int i = blockIdx.x * blockDim.x + threadIdx.x;
    if (i < N_NEURONS) v[i] = (i < INPUT_SIZE) ? x[i] : 0.0f;
}

// Block (r,c): stream edge stripe, LDS-bin dsts in [r*BIN, r*BIN+BIN), flush
// to private partial slab (no device atomics anywhere).
__global__ void scatter_binned(const float* __restrict__ w,
                               const int*   __restrict__ src,
                               const int*   __restrict__ dst,
                               const float* __restrict__ v,
                               float*       __restrict__ partials,
                               int C) {
    __shared__ float bins[BIN];
    const int r = blockIdx.x / C;
    const int c = blockIdx.x % C;
    const int lo = r * BIN;
    const int hi = lo + BIN;

    for (int j = threadIdx.x; j < BIN; j += blockDim.x) bins[j] = 0.0f;
    __syncthreads();

    const int4*   src4 = (const int4*)src;
    const int4*   dst4 = (const int4*)dst;
    const float4* w4v  = (const float4*)w;
    const int stride = C * blockDim.x;

    for (int u = c * blockDim.x + threadIdx.x; u < VEC4; u += stride) {
        const int4   s4 = src4[u];
        const int4   d4 = dst4[u];
        const float4 wv = w4v[u];
        int   s[4] = {s4.x, s4.y, s4.z, s4.w};
        int   d[4] = {d4.x, d4.y, d4.z, d4.w};
        float ww[4] = {wv.x, wv.y, wv.z, wv.w};
#pragma unroll
        for (int k = 0; k < 4; ++k) {
            if (d[k] >= lo && d[k] < hi) {
                atomicAdd(&bins[d[k] - lo], v[s[k]] * ww[k]);
            }
        }
    }
    __syncthreads();

    float* out = partials + ((size_t)(r * C + c)) * BIN;
    for (int j = threadIdx.x; j < BIN; j += blockDim.x) out[j] = bins[j];
}

// Sum C partials per neuron, add bias, tanh (except output window), write v
// (and d_out on the final step). Each thread handles 4 neurons (BIN % 4 == 0,
// so a float4 group never crosses a range boundary).
__global__ void reduce_update(const float* __restrict__ partials,
                              const float* __restrict__ bias,
                              float* __restrict__ v,
                              float* __restrict__ out,
                              int C, int write_out) {
    int i4 = 4 * (blockIdx.x * blockDim.x + threadIdx.x);
    if (i4 >= N_NEURONS) return;
    const int r = i4 / BIN;
    const int j = i4 - r * BIN;
    const float* base = partials + ((size_t)r * C) * BIN + j;
    float4 acc = {0.f, 0.f, 0.f, 0.f};
    for (int c = 0; c < C; ++c) {
        float4 p = *(const float4*)(base + (size_t)c * BIN);
        acc.x += p.x; acc.y += p.y; acc.z += p.z; acc.w += p.w;
    }
    float av[4] = {acc.x, acc.y, acc.z, acc.w};
#pragma unroll
    for (int k = 0; k < 4; ++k) {
        int i = i4 + k;
        float val = av[k] + ((i >= INPUT_SIZE) ? bias[i - INPUT_SIZE] : 0.0f);
        float nv  = (i < N_NEURONS - OUTPUT_SIZE) ? tanhf(val) : val;
        v[i] = nv;
        if (write_out && i >= N_NEURONS - OUTPUT_SIZE)
            out[i - (N_NEURONS - OUTPUT_SIZE)] = val;
    }
}

// ---- fallback (tiny ws): round-1 device-atomic path ----
__global__ void init_state_fb(const float* __restrict__ x,
                              const float* __restrict__ bias,
                              float* __restrict__ v, float* __restrict__ nxt) {
    int i = blockIdx.x * blockDim.x + threadIdx.x;
    if (i < N_NEURONS) {
        v[i]   = (i < INPUT_SIZE) ? x[i] : 0.0f;
        nxt[i] = (i >= INPUT_SIZE) ? bias[i - INPUT_SIZE] : 0.0f;
    }
}
__global__ void scatter_atomic(const float* __restrict__ w,
                               const int* __restrict__ src,
                               const int* __restrict__ dst,
                               const float* __restrict__ v,
                               float* __restrict__ nxt) {
    int t = blockIdx.x * blockDim.x + threadIdx.x;
    if (t < VEC4) {
        const int4   s4 = ((const int4*)src)[t];
        const int4   d4 = ((const int4*)dst)[t];
        const float4 w4 = ((const float4*)w)[t];
        atomicAdd(&nxt[d4.x], v[s4.x] * w4.x);
        atomicAdd(&nxt[d4.y], v[s4.y] * w4.y);
        atomicAdd(&nxt[d4.z], v[s4.z] * w4.z);
        atomicAdd(&nxt[d4.w], v[s4.w] * w4.w);
    }
}
__global__ void update_fb(const float* __restrict__ bias, float* __restrict__ v,
                          float* __restrict__ nxt, float* __restrict__ out,
                          int write_out) {
    int i = blockIdx.x * blockDim.x + threadIdx.x;
    if (i < N_NEURONS) {
        float val  = nxt[i];
        float nv   = (i < N_NEURONS - OUTPUT_SIZE) ? tanhf(val) : val;
        v[i]   = nv;
        nxt[i] = (i >= INPUT_SIZE) ? bias[i - INPUT_SIZE] : 0.0f;
        if (write_out && i >= N_NEURONS - OUTPUT_SIZE)
            out[i - (N_NEURONS - OUTPUT_SIZE)] = val;
    }
}

extern "C" void kernel_launch(void* const* d_in, const int* in_sizes, int n_in,
                              void* d_out, int out_size, void* d_ws, size_t ws_size,
                              hipStream_t stream) {
    const float* x    = (const float*)d_in[0];
    const float* w    = (const float*)d_in[1];
    const float* bias = (const float*)d_in[2];
    const int*   src  = (const int*)d_in[3];
    const int*   dst  = (const int*)d_in[4];
    float* out = (float*)d_out;

    float* v = (float*)d_ws;

    // partial copies that fit: ws holds v (N floats) + C*N floats of partials
    long C = (long)(ws_size / 4 / N_NEURONS) - 1;
    if (C > 64) C = 64;

    const int blk = 256;
    const int grid_n = (N_NEURONS + blk - 1) / blk;

    if (C >= 8) {
        float* partials = v + N_NEURONS;
        init_state<<<grid_n, blk, 0, stream>>>(x, v);
        const int red_grid = (N_NEURONS / 4 + blk - 1) / blk;
        for (int s = 0; s < STEPS; ++s) {
            scatter_binned<<<RANGES * (int)C, SCAT_BLK, 0, stream>>>(
                w, src, dst, v, partials, (int)C);
            reduce_update<<<red_grid, blk, 0, stream>>>(
                partials, bias, v, out, (int)C, s == STEPS - 1 ? 1 : 0);
        }
    } else {
        float* nxt = v + N_NEURONS;
        init_state_fb<<<grid_n, blk, 0, stream>>>(x, bias, v, nxt);
        const int grid_e = (VEC4 + blk - 1) / blk;
        for (int s = 0; s < STEPS; ++s) {
            scatter_atomic<<<grid_e, blk, 0, stream>>>(w, src, dst, v, nxt);
            update_fb<<<grid_n, blk, 0, stream>>>(bias, v, nxt, out,
                                                  s == STEPS - 1 ? 1 : 0);
        }
    }
}

// Round 3
// 472.174 us; speedup vs baseline: 3.4929x; 1.0384x over previous
//
#include <hip/hip_runtime.h>

#define N_NEURONS   100000
#define INPUT_SIZE  1024
#define OUTPUT_SIZE 256
#define E_SYN       10000000
#define STEPS       3

#define RANGES      8
#define BIN         12500          // neurons per range; RANGES*BIN == N_NEURONS
#define SCAT_BLK    512
#define CBLK        64             // blocks per range in scatter
#define CAP         1280000        // per-range bucket capacity (mean 1.25M, sigma ~1K)
#define B_CNT       800            // reorder blocks
#define CH          12500          // edges per reorder block: 800*12500 == E_SYN
#define VEC4        (E_SYN / 4)

// v init + zero the 8 global range cursors
__global__ void init_all(const float* __restrict__ x, float* __restrict__ v,
                         int* __restrict__ gcur) {
    int i = blockIdx.x * blockDim.x + threadIdx.x;
    if (i < N_NEURONS) v[i] = (i < INPUT_SIZE) ? x[i] : 0.0f;
    if (i < RANGES) gcur[i] = 0;
}

// One-time: partition edges into range-major buckets. Two-phase per block:
// LDS histogram -> one device atomic per range to reserve slots -> write.
__global__ void reorder_partition(const float* __restrict__ w,
                                  const int*   __restrict__ src,
                                  const int*   __restrict__ dst,
                                  float* __restrict__ w_s,
                                  int2*  __restrict__ sd_s,
                                  int*   __restrict__ gcur) {
    __shared__ int cnt[RANGES][9];   // [r][lane&7], padded
    __shared__ int cursor[RANGES];
    const int tid = threadIdx.x;
    const int l8 = tid & 7;
    if (tid < RANGES * 9) ((int*)cnt)[tid] = 0;
    __syncthreads();

    const int beg = blockIdx.x * CH;
    const int end = beg + CH;
    for (int e = beg + tid; e < end; e += blockDim.x) {
        int r = dst[e] / BIN;
        atomicAdd(&cnt[r][l8], 1);
    }
    __syncthreads();
    if (tid < RANGES) {
        int s = 0;
#pragma unroll
        for (int l = 0; l < 8; ++l) s += cnt[tid][l];
        cursor[tid] = tid * CAP + atomicAdd(&gcur[tid], s);
    }
    __syncthreads();
    for (int e = beg + tid; e < end; e += blockDim.x) {
        int d = dst[e];
        int r = d / BIN;
        int pos = atomicAdd(&cursor[r], 1);
        w_s[pos]  = w[e];
        sd_s[pos] = make_int2(src[e], d);
    }
}

// Per step: block (r,c) scans a stripe of bucket r only; LDS bins; flush partials.
__global__ void scatter_sorted(const float* __restrict__ w_s,
                               const int2*  __restrict__ sd_s,
                               const int*   __restrict__ gcur,
                               const float* __restrict__ v,
                               float*       __restrict__ partials) {
    __shared__ float bins[BIN];
    const int r  = blockIdx.x / CBLK;
    const int c  = blockIdx.x % CBLK;
    const int lo = r * BIN;
    for (int j = threadIdx.x; j < BIN; j += blockDim.x) bins[j] = 0.0f;
    __syncthreads();

    const int beg = r * CAP;
    const int end = beg + gcur[r];
    const int stride = CBLK * blockDim.x;
    for (int u = beg + c * blockDim.x + threadIdx.x; u < end; u += stride) {
        int2  sd = sd_s[u];
        float m  = v[sd.x] * w_s[u];
        atomicAdd(&bins[sd.y - lo], m);
    }
    __syncthreads();

    float* o = partials + (size_t)(r * CBLK + c) * BIN;
    for (int j = threadIdx.x; j < BIN; j += blockDim.x) o[j] = bins[j];
}

// Sum CBLK partials per neuron, add bias, tanh (except outputs), write v/out.
__global__ void reduce_update(const float* __restrict__ partials,
                              const float* __restrict__ bias,
                              float* __restrict__ v,
                              float* __restrict__ out,
                              int C, int write_out) {
    int i4 = 4 * (blockIdx.x * blockDim.x + threadIdx.x);
    if (i4 >= N_NEURONS) return;
    const int r = i4 / BIN;
    const int j = i4 - r * BIN;
    const float* base = partials + ((size_t)r * C) * BIN + j;
    float4 acc = {0.f, 0.f, 0.f, 0.f};
    for (int c = 0; c < C; ++c) {
        float4 p = *(const float4*)(base + (size_t)c * BIN);
        acc.x += p.x; acc.y += p.y; acc.z += p.z; acc.w += p.w;
    }
    float av[4] = {acc.x, acc.y, acc.z, acc.w};
#pragma unroll
    for (int k = 0; k < 4; ++k) {
        int i = i4 + k;
        float val = av[k] + ((i >= INPUT_SIZE) ? bias[i - INPUT_SIZE] : 0.0f);
        float nv  = (i < N_NEURONS - OUTPUT_SIZE) ? tanhf(val) : val;
        v[i] = nv;
        if (write_out && i >= N_NEURONS - OUTPUT_SIZE)
            out[i - (N_NEURONS - OUTPUT_SIZE)] = val;
    }
}

// ---- fallback (small ws): round-2 multi-pass binned path ----
__global__ void init_state_fb(const float* __restrict__ x, float* __restrict__ v) {
    int i = blockIdx.x * blockDim.x + threadIdx.x;
    if (i < N_NEURONS) v[i] = (i < INPUT_SIZE) ? x[i] : 0.0f;
}
__global__ void scatter_binned(const float* __restrict__ w,
                               const int*   __restrict__ src,
                               const int*   __restrict__ dst,
                               const float* __restrict__ v,
                               float*       __restrict__ partials,
                               int C) {
    __shared__ float bins[BIN];
    const int r = blockIdx.x / C;
    const int c = blockIdx.x % C;
    const int lo = r * BIN;
    const int hi = lo + BIN;
    for (int j = threadIdx.x; j < BIN; j += blockDim.x) bins[j] = 0.0f;
    __syncthreads();
    const int4*   src4 = (const int4*)src;
    const int4*   dst4 = (const int4*)dst;
    const float4* w4v  = (const float4*)w;
    const int stride = C * blockDim.x;
    for (int u = c * blockDim.x + threadIdx.x; u < VEC4; u += stride) {
        const int4   s4 = src4[u];
        const int4   d4 = dst4[u];
        const float4 wv = w4v[u];
        int   s[4] = {s4.x, s4.y, s4.z, s4.w};
        int   d[4] = {d4.x, d4.y, d4.z, d4.w};
        float ww[4] = {wv.x, wv.y, wv.z, wv.w};
#pragma unroll
        for (int k = 0; k < 4; ++k)
            if (d[k] >= lo && d[k] < hi)
                atomicAdd(&bins[d[k] - lo], v[s[k]] * ww[k]);
    }
    __syncthreads();
    float* o = partials + ((size_t)(r * C + c)) * BIN;
    for (int j = threadIdx.x; j < BIN; j += blockDim.x) o[j] = bins[j];
}

extern "C" void kernel_launch(void* const* d_in, const int* in_sizes, int n_in,
                              void* d_out, int out_size, void* d_ws, size_t ws_size,
                              hipStream_t stream) {
    const float* x    = (const float*)d_in[0];
    const float* w    = (const float*)d_in[1];
    const float* bias = (const float*)d_in[2];
    const int*   src  = (const int*)d_in[3];
    const int*   dst  = (const int*)d_in[4];
    float* out = (float*)d_out;

    const int blk = 256;
    const int grid_n   = (N_NEURONS + blk - 1) / blk;
    const int red_grid = (N_NEURONS / 4 + blk - 1) / blk;

    // sorted-path ws layout
    float* v        = (float*)d_ws;
    float* partials = v + N_NEURONS;
    float* w_s      = partials + (size_t)RANGES * CBLK * BIN;
    int2*  sd_s     = (int2*)(w_s + (size_t)RANGES * CAP);
    int*   gcur     = (int*)(sd_s + (size_t)RANGES * CAP);
    size_t need = (size_t)(gcur + RANGES) - (size_t)d_ws;

    if (ws_size >= need) {
        init_all<<<grid_n, blk, 0, stream>>>(x, v, gcur);
        reorder_partition<<<B_CNT, blk, 0, stream>>>(w, src, dst, w_s, sd_s, gcur);
        for (int s = 0; s < STEPS; ++s) {
            scatter_sorted<<<RANGES * CBLK, SCAT_BLK, 0, stream>>>(
                w_s, sd_s, gcur, v, partials);
            reduce_update<<<red_grid, blk, 0, stream>>>(
                partials, bias, v, out, CBLK, s == STEPS - 1 ? 1 : 0);
        }
    } else {
        // fallback: multi-pass rescan (round-2 behavior)
        long C = (long)(ws_size / 4 / N_NEURONS) - 1;
        if (C > 64) C = 64;
        if (C < 1) C = 1;
        float* part_fb = v + N_NEURONS;
        init_state_fb<<<grid_n, blk, 0, stream>>>(x, v);
        for (int s = 0; s < STEPS; ++s) {
            scatter_binned<<<RANGES * (int)C, SCAT_BLK, 0, stream>>>(
                w, src, dst, v, part_fb, (int)C);
            reduce_update<<<red_grid, blk, 0, stream>>>(
                part_fb, bias, v, out, (int)C, s == STEPS - 1 ? 1 : 0);
        }
    }
}

// Round 4
// 461.079 us; speedup vs baseline: 3.5770x; 1.0241x over previous
//
#include <hip/hip_runtime.h>

#define N_NEURONS   100000
#define INPUT_SIZE  1024
#define OUTPUT_SIZE 256
#define E_SYN       10000000
#define STEPS       3

#define RANGES      8
#define BIN         12500          // neurons per range; RANGES*BIN == N_NEURONS
#define SCAT_BLK    512
#define CBLK        96             // blocks per range: 768 blocks = 3/CU at 50KB LDS
#define CAP         1280000        // per-range bucket capacity (mean 1.25M, ~28 sigma)
#define RB_BLK      256            // reorder block size
#define CH          5000           // edges per reorder block
#define B_CNT       2000           // 2000 * 5000 == E_SYN
#define VEC4        (E_SYN / 4)

// v init + zero the 8 global range cursors
__global__ void init_all(const float* __restrict__ x, float* __restrict__ v,
                         int* __restrict__ gcur) {
    int i = blockIdx.x * blockDim.x + threadIdx.x;
    if (i < N_NEURONS) v[i] = (i < INPUT_SIZE) ? x[i] : 0.0f;
    if (i < RANGES) gcur[i] = 0;
}

// One-time partition into range-major buckets of packed 8B records
// code = (src << 14) | dst_local. Wave-aggregated ranking via ballot:
// 8 LDS atomics per wave-iteration instead of 64.
__global__ void reorder_partition(const float* __restrict__ w,
                                  const int*   __restrict__ src,
                                  const int*   __restrict__ dst,
                                  int2* __restrict__ recs,
                                  int*  __restrict__ gcur) {
    __shared__ int cnt[RANGES];
    __shared__ int cursor[RANGES];
    const int tid  = threadIdx.x;
    const int lane = tid & 63;
    const unsigned long long ltmask = (1ull << lane) - 1ull;
    if (tid < RANGES) cnt[tid] = 0;
    __syncthreads();

    const int beg  = blockIdx.x * CH;
    const int endx = beg + CH;
    const int ITER = (CH + RB_BLK - 1) / RB_BLK;

    // phase 1: per-wave histogram via ballot; lane rr accumulates count of range rr
    int wcnt = 0;
    for (int it = 0; it < ITER; ++it) {
        int  e  = beg + it * RB_BLK + tid;
        bool ok = (e < endx);
        int  r  = ok ? (dst[e] / BIN) : -1;
#pragma unroll
        for (int rr = 0; rr < RANGES; ++rr) {
            unsigned long long mask = __ballot(r == rr);
            if (lane == rr) wcnt += __popcll(mask);
        }
    }
    if (lane < RANGES) atomicAdd(&cnt[lane], wcnt);
    __syncthreads();
    if (tid < RANGES) cursor[tid] = tid * CAP + atomicAdd(&gcur[tid], cnt[tid]);
    __syncthreads();

    // phase 2: ballot-rank within wave, 8 LDS cursor atomics per wave-iter
    for (int it = 0; it < ITER; ++it) {
        int  e  = beg + it * RB_BLK + tid;
        bool ok = (e < endx);
        int  d  = ok ? dst[e] : 0;
        int  r  = ok ? (d / BIN) : -1;
        int  pos = 0;
#pragma unroll
        for (int rr = 0; rr < RANGES; ++rr) {
            unsigned long long mask = __ballot(r == rr);
            int tot = __popcll(mask);
            int b = 0;
            if (lane == rr) b = atomicAdd(&cursor[rr], tot);
            b = __shfl(b, rr, 64);
            if (r == rr) pos = b + __popcll(mask & ltmask);
        }
        if (ok) {
            int code = (src[e] << 14) | (d - r * BIN);
            recs[pos] = make_int2(code, __float_as_int(w[e]));
        }
    }
}

// Per step: block (r,c) streams a stripe of bucket r (2 packed edges per int4),
// LDS-bins, flushes private partial slab. No device atomics.
__global__ __launch_bounds__(SCAT_BLK) void scatter_sorted(
        const int2* __restrict__ recs,
        const int*  __restrict__ gcur,
        const float* __restrict__ v,
        float* __restrict__ partials) {
    __shared__ float bins[BIN];
    const int r = blockIdx.x / CBLK;
    const int c = blockIdx.x % CBLK;
    for (int j = threadIdx.x; j < BIN; j += SCAT_BLK) bins[j] = 0.0f;
    __syncthreads();

    const int cnt   = gcur[r];
    const int npair = cnt >> 1;
    const int4* base4 = (const int4*)(recs + (size_t)r * CAP);
    const int stride = CBLK * SCAT_BLK;
    for (int u = c * SCAT_BLK + threadIdx.x; u < npair; u += stride) {
        int4 p = base4[u];
        atomicAdd(&bins[p.x & 16383], v[p.x >> 14] * __int_as_float(p.y));
        atomicAdd(&bins[p.z & 16383], v[p.z >> 14] * __int_as_float(p.w));
    }
    if ((cnt & 1) && c == 0 && threadIdx.x == 0) {
        int2 p = recs[(size_t)r * CAP + cnt - 1];
        atomicAdd(&bins[p.x & 16383], v[p.x >> 14] * __int_as_float(p.y));
    }
    __syncthreads();
    float* o = partials + (size_t)(r * CBLK + c) * BIN;
    for (int j = threadIdx.x; j < BIN; j += SCAT_BLK) o[j] = bins[j];
}

// Sum C partials per neuron, add bias, tanh (except outputs), write v/out.
__global__ void reduce_update(const float* __restrict__ partials,
                              const float* __restrict__ bias,
                              float* __restrict__ v,
                              float* __restrict__ out,
                              int C, int write_out) {
    int i4 = 4 * (blockIdx.x * blockDim.x + threadIdx.x);
    if (i4 >= N_NEURONS) return;
    const int r = i4 / BIN;
    const int j = i4 - r * BIN;
    const float* base = partials + ((size_t)r * C) * BIN + j;
    float4 acc = {0.f, 0.f, 0.f, 0.f};
    for (int c = 0; c < C; ++c) {
        float4 p = *(const float4*)(base + (size_t)c * BIN);
        acc.x += p.x; acc.y += p.y; acc.z += p.z; acc.w += p.w;
    }
    float av[4] = {acc.x, acc.y, acc.z, acc.w};
#pragma unroll
    for (int k = 0; k < 4; ++k) {
        int i = i4 + k;
        float val = av[k] + ((i >= INPUT_SIZE) ? bias[i - INPUT_SIZE] : 0.0f);
        float nv  = (i < N_NEURONS - OUTPUT_SIZE) ? tanhf(val) : val;
        v[i] = nv;
        if (write_out && i >= N_NEURONS - OUTPUT_SIZE)
            out[i - (N_NEURONS - OUTPUT_SIZE)] = val;
    }
}

// ---- fallback (small ws): multi-pass binned rescan path ----
__global__ void init_state_fb(const float* __restrict__ x, float* __restrict__ v) {
    int i = blockIdx.x * blockDim.x + threadIdx.x;
    if (i < N_NEURONS) v[i] = (i < INPUT_SIZE) ? x[i] : 0.0f;
}
__global__ void scatter_binned(const float* __restrict__ w,
                               const int*   __restrict__ src,
                               const int*   __restrict__ dst,
                               const float* __restrict__ v,
                               float*       __restrict__ partials,
                               int C) {
    __shared__ float bins[BIN];
    const int r = blockIdx.x / C;
    const int c = blockIdx.x % C;
    const int lo = r * BIN;
    const int hi = lo + BIN;
    for (int j = threadIdx.x; j < BIN; j += blockDim.x) bins[j] = 0.0f;
    __syncthreads();
    const int4*   src4 = (const int4*)src;
    const int4*   dst4 = (const int4*)dst;
    const float4* w4v  = (const float4*)w;
    const int stride = C * blockDim.x;
    for (int u = c * blockDim.x + threadIdx.x; u < VEC4; u += stride) {
        const int4   s4 = src4[u];
        const int4   d4 = dst4[u];
        const float4 wv = w4v[u];
        int   s[4] = {s4.x, s4.y, s4.z, s4.w};
        int   d[4] = {d4.x, d4.y, d4.z, d4.w};
        float ww[4] = {wv.x, wv.y, wv.z, wv.w};
#pragma unroll
        for (int k = 0; k < 4; ++k)
            if (d[k] >= lo && d[k] < hi)
                atomicAdd(&bins[d[k] - lo], v[s[k]] * ww[k]);
    }
    __syncthreads();
    float* o = partials + ((size_t)(r * C + c)) * BIN;
    for (int j = threadIdx.x; j < BIN; j += blockDim.x) o[j] = bins[j];
}

extern "C" void kernel_launch(void* const* d_in, const int* in_sizes, int n_in,
                              void* d_out, int out_size, void* d_ws, size_t ws_size,
                              hipStream_t stream) {
    const float* x    = (const float*)d_in[0];
    const float* w    = (const float*)d_in[1];
    const float* bias = (const float*)d_in[2];
    const int*   src  = (const int*)d_in[3];
    const int*   dst  = (const int*)d_in[4];
    float* out = (float*)d_out;

    const int blk = 256;
    const int grid_n   = (N_NEURONS + blk - 1) / blk;
    const int red_grid = (N_NEURONS / 4 + blk - 1) / blk;

    // sorted-path ws layout: v | partials | recs | gcur
    float* v        = (float*)d_ws;
    float* partials = v + N_NEURONS;
    int2*  recs     = (int2*)(partials + (size_t)RANGES * CBLK * BIN);
    int*   gcur     = (int*)(recs + (size_t)RANGES * CAP);
    size_t need = (size_t)((char*)(gcur + RANGES) - (char*)d_ws);

    if (ws_size >= need) {
        init_all<<<grid_n, blk, 0, stream>>>(x, v, gcur);
        reorder_partition<<<B_CNT, RB_BLK, 0, stream>>>(w, src, dst, recs, gcur);
        for (int s = 0; s < STEPS; ++s) {
            scatter_sorted<<<RANGES * CBLK, SCAT_BLK, 0, stream>>>(
                recs, gcur, v, partials);
            reduce_update<<<red_grid, blk, 0, stream>>>(
                partials, bias, v, out, CBLK, s == STEPS - 1 ? 1 : 0);
        }
    } else {
        long C = (long)(ws_size / 4 / N_NEURONS) - 1;
        if (C > 64) C = 64;
        if (C < 1) C = 1;
        float* part_fb = v + N_NEURONS;
        init_state_fb<<<grid_n, blk, 0, stream>>>(x, v);
        for (int s = 0; s < STEPS; ++s) {
            scatter_binned<<<RANGES * (int)C, SCAT_BLK, 0, stream>>>(
                w, src, dst, v, part_fb, (int)C);
            reduce_update<<<red_grid, blk, 0, stream>>>(
                part_fb, bias, v, out, (int)C, s == STEPS - 1 ? 1 : 0);
        }
    }
}

// Round 5
// 420.262 us; speedup vs baseline: 3.9244x; 1.0971x over previous
//
#include <hip/hip_runtime.h>

#define N_NEURONS   100000
#define INPUT_SIZE  1024
#define OUTPUT_SIZE 256
#define E_SYN       10000000
#define STEPS       3

#define RANGES      8
#define BIN         12500          // neurons per range; RANGES*BIN == N_NEURONS
#define SCAT_BLK    512
#define CBLK        96             // blocks per range: 768 blocks = 3/CU at 50KB LDS
#define RG          8              // reduce stage-1 groups
#define RSL         (CBLK / RG)    // 12 slabs per group
#define CAP         1280000        // per-range bucket capacity (mean 1.25M, ~28 sigma)
#define RB_BLK      256            // reorder block size
#define CH          4000           // edges per reorder block
#define B_CNT       2500           // 2500 * 4000 == E_SYN
#define VEC4        (E_SYN / 4)

// v init + zero the 8 global range cursors
__global__ void init_all(const float* __restrict__ x, float* __restrict__ v,
                         int* __restrict__ gcur) {
    int i = blockIdx.x * blockDim.x + threadIdx.x;
    if (i < N_NEURONS) v[i] = (i < INPUT_SIZE) ? x[i] : 0.0f;
    if (i < RANGES) gcur[i] = 0;
}

// One-time partition into range-major buckets of packed 8B records
// code = (src << 14) | dst_local. Bit-sliced ballot ranking: 4 ballots +
// scalar mask combines; 1 LDS atomic + 1 LDS write/read per wave-iter.
__global__ __launch_bounds__(RB_BLK) void reorder_partition(
        const float* __restrict__ w,
        const int*   __restrict__ src,
        const int*   __restrict__ dst,
        int2* __restrict__ recs,
        int*  __restrict__ gcur) {
    __shared__ int cnt[RANGES];
    __shared__ int cursor[RANGES];
    __shared__ int wbase[RB_BLK / 64][RANGES];
    const int tid  = threadIdx.x;
    const int lane = tid & 63;
    const int wv   = tid >> 6;
    const unsigned long long ltmask = (1ull << lane) - 1ull;
    if (tid < RANGES) cnt[tid] = 0;
    __syncthreads();

    const int beg  = blockIdx.x * CH;
    const int endx = beg + CH;
    const int ITER = (CH + RB_BLK - 1) / RB_BLK;
    const int* wi  = (const int*)w;

    // phase 1: wave histogram, fully scalar after 4 ballots
    int h[RANGES] = {0, 0, 0, 0, 0, 0, 0, 0};
    for (int it = 0; it < ITER; ++it) {
        int  e  = beg + it * RB_BLK + tid;
        bool ok = (e < endx);
        int  d  = ok ? dst[e] : 0;
        int  r  = d / BIN;
        unsigned long long okm = __ballot(ok);
        unsigned long long b0  = __ballot(r & 1);
        unsigned long long b1  = __ballot(r & 2);
        unsigned long long b2  = __ballot(r & 4);
#pragma unroll
        for (int rr = 0; rr < RANGES; ++rr) {
            unsigned long long m = ((rr & 1) ? b0 : ~b0) &
                                   ((rr & 2) ? b1 : ~b1) &
                                   ((rr & 4) ? b2 : ~b2) & okm;
            h[rr] += __popcll(m);
        }
    }
    if (lane < RANGES) {
        int t = h[0];
#pragma unroll
        for (int rr = 1; rr < RANGES; ++rr) if (lane == rr) t = h[rr];
        atomicAdd(&cnt[lane], t);
    }
    __syncthreads();
    if (tid < RANGES) cursor[tid] = tid * CAP + atomicAdd(&gcur[tid], cnt[tid]);
    __syncthreads();

    // phase 2: rank + write. One LDS atomic per wave-iter, base via LDS.
    for (int it = 0; it < ITER; ++it) {
        int  e  = beg + it * RB_BLK + tid;
        bool ok = (e < endx);
        int  d  = ok ? dst[e] : 0;
        int  sv = ok ? src[e] : 0;
        int  wb = ok ? wi[e]  : 0;
        int  r  = d / BIN;
        unsigned long long okm = __ballot(ok);
        unsigned long long b0  = __ballot(r & 1);
        unsigned long long b1  = __ballot(r & 2);
        unsigned long long b2  = __ballot(r & 4);
        // per-lane: count of range==lane (meaningful for lanes 0-7)
        unsigned long long s0 = (lane & 1) ? b0 : ~b0;
        unsigned long long s1 = (lane & 2) ? b1 : ~b1;
        unsigned long long s2 = (lane & 4) ? b2 : ~b2;
        int tot = __popcll(s0 & s1 & s2 & okm);
        if (lane < RANGES) wbase[wv][lane] = atomicAdd(&cursor[lane], tot);
        // my own range's mask + base
        unsigned long long m0 = (r & 1) ? b0 : ~b0;
        unsigned long long m1 = (r & 2) ? b1 : ~b1;
        unsigned long long m2 = (r & 4) ? b2 : ~b2;
        unsigned long long mym = m0 & m1 & m2 & okm;
        int base = wbase[wv][r];   // same-wave DS ordering guarantees visibility
        int pos  = base + __popcll(mym & ltmask);
        if (ok) recs[pos] = make_int2((sv << 14) | (d - r * BIN), wb);
    }
}

// Per step: block (r,c) streams a stripe of bucket r (2 packed edges per int4,
// unrolled x2 for 4 gathers in flight), LDS-bins, flushes partial slab.
__global__ __launch_bounds__(SCAT_BLK) void scatter_sorted(
        const int2* __restrict__ recs,
        const int*  __restrict__ gcur,
        const float* __restrict__ v,
        float* __restrict__ partials) {
    __shared__ float bins[BIN];
    const int r = blockIdx.x / CBLK;
    const int c = blockIdx.x % CBLK;
    for (int j = threadIdx.x; j < BIN; j += SCAT_BLK) bins[j] = 0.0f;
    __syncthreads();

    const int cnt   = gcur[r];
    const int npair = cnt >> 1;
    const int4* base4 = (const int4*)(recs + (size_t)r * CAP);
    const int stride = CBLK * SCAT_BLK;
    int u = c * SCAT_BLK + threadIdx.x;
    for (; u + stride < npair; u += 2 * stride) {
        int4 a = base4[u];
        int4 b = base4[u + stride];
        float va0 = v[a.x >> 14];
        float va1 = v[a.z >> 14];
        float vb0 = v[b.x >> 14];
        float vb1 = v[b.z >> 14];
        atomicAdd(&bins[a.x & 16383], va0 * __int_as_float(a.y));
        atomicAdd(&bins[a.z & 16383], va1 * __int_as_float(a.w));
        atomicAdd(&bins[b.x & 16383], vb0 * __int_as_float(b.y));
        atomicAdd(&bins[b.z & 16383], vb1 * __int_as_float(b.w));
    }
    if (u < npair) {
        int4 a = base4[u];
        atomicAdd(&bins[a.x & 16383], v[a.x >> 14] * __int_as_float(a.y));
        atomicAdd(&bins[a.z & 16383], v[a.z >> 14] * __int_as_float(a.w));
    }
    if ((cnt & 1) && c == 0 && threadIdx.x == 0) {
        int2 p = recs[(size_t)r * CAP + cnt - 1];
        atomicAdd(&bins[p.x & 16383], v[p.x >> 14] * __int_as_float(p.y));
    }
    __syncthreads();
    float* o = partials + (size_t)(r * CBLK + c) * BIN;
    for (int j = threadIdx.x; j < BIN; j += SCAT_BLK) o[j] = bins[j];
}

// Reduce stage 1: group g sums RSL slabs -> p2[g][N]. 8x the parallelism.
__global__ void reduce_stage1(const float* __restrict__ partials,
                              float* __restrict__ p2) {
    int i4 = 4 * (blockIdx.x * blockDim.x + threadIdx.x);
    if (i4 >= N_NEURONS) return;
    const int g = blockIdx.y;
    const int r = i4 / BIN;
    const int j = i4 - r * BIN;
    const float* base = partials + ((size_t)(r * CBLK + g * RSL)) * BIN + j;
    float4 acc = {0.f, 0.f, 0.f, 0.f};
#pragma unroll
    for (int c = 0; c < RSL; ++c) {
        float4 p = *(const float4*)(base + (size_t)c * BIN);
        acc.x += p.x; acc.y += p.y; acc.z += p.z; acc.w += p.w;
    }
    *(float4*)(p2 + (size_t)g * N_NEURONS + i4) = acc;
}

// Reduce stage 2: sum 8 group-partials, add bias, tanh (except outputs).
__global__ void reduce_stage2(const float* __restrict__ p2,
                              const float* __restrict__ bias,
                              float* __restrict__ v,
                              float* __restrict__ out,
                              int write_out) {
    int i4 = 4 * (blockIdx.x * blockDim.x + threadIdx.x);
    if (i4 >= N_NEURONS) return;
    float4 acc = {0.f, 0.f, 0.f, 0.f};
#pragma unroll
    for (int g = 0; g < RG; ++g) {
        float4 p = *(const float4*)(p2 + (size_t)g * N_NEURONS + i4);
        acc.x += p.x; acc.y += p.y; acc.z += p.z; acc.w += p.w;
    }
    float av[4] = {acc.x, acc.y, acc.z, acc.w};
#pragma unroll
    for (int k = 0; k < 4; ++k) {
        int i = i4 + k;
        float val = av[k] + ((i >= INPUT_SIZE) ? bias[i - INPUT_SIZE] : 0.0f);
        float nv  = (i < N_NEURONS - OUTPUT_SIZE) ? tanhf(val) : val;
        v[i] = nv;
        if (write_out && i >= N_NEURONS - OUTPUT_SIZE)
            out[i - (N_NEURONS - OUTPUT_SIZE)] = val;
    }
}

// ---- fallback (small ws): multi-pass binned rescan path ----
__global__ void init_state_fb(const float* __restrict__ x, float* __restrict__ v) {
    int i = blockIdx.x * blockDim.x + threadIdx.x;
    if (i < N_NEURONS) v[i] = (i < INPUT_SIZE) ? x[i] : 0.0f;
}
__global__ void scatter_binned(const float* __restrict__ w,
                               const int*   __restrict__ src,
                               const int*   __restrict__ dst,
                               const float* __restrict__ v,
                               float*       __restrict__ partials,
                               int C) {
    __shared__ float bins[BIN];
    const int r = blockIdx.x / C;
    const int c = blockIdx.x % C;
    const int lo = r * BIN;
    const int hi = lo + BIN;
    for (int j = threadIdx.x; j < BIN; j += blockDim.x) bins[j] = 0.0f;
    __syncthreads();
    const int4*   src4 = (const int4*)src;
    const int4*   dst4 = (const int4*)dst;
    const float4* w4v  = (const float4*)w;
    const int stride = C * blockDim.x;
    for (int u = c * blockDim.x + threadIdx.x; u < VEC4; u += stride) {
        const int4   s4 = src4[u];
        const int4   d4 = dst4[u];
        const float4 wv = w4v[u];
        int   s[4] = {s4.x, s4.y, s4.z, s4.w};
        int   d[4] = {d4.x, d4.y, d4.z, d4.w};
        float ww[4] = {wv.x, wv.y, wv.z, wv.w};
#pragma unroll
        for (int k = 0; k < 4; ++k)
            if (d[k] >= lo && d[k] < hi)
                atomicAdd(&bins[d[k] - lo], v[s[k]] * ww[k]);
    }
    __syncthreads();
    float* o = partials + ((size_t)(r * C + c)) * BIN;
    for (int j = threadIdx.x; j < BIN; j += blockDim.x) o[j] = bins[j];
}
__global__ void reduce_update_fb(const float* __restrict__ partials,
                                 const float* __restrict__ bias,
                                 float* __restrict__ v,
                                 float* __restrict__ out,
                                 int C, int write_out) {
    int i4 = 4 * (blockIdx.x * blockDim.x + threadIdx.x);
    if (i4 >= N_NEURONS) return;
    const int r = i4 / BIN;
    const int j = i4 - r * BIN;
    const float* base = partials + ((size_t)r * C) * BIN + j;
    float4 acc = {0.f, 0.f, 0.f, 0.f};
    for (int c = 0; c < C; ++c) {
        float4 p = *(const float4*)(base + (size_t)c * BIN);
        acc.x += p.x; acc.y += p.y; acc.z += p.z; acc.w += p.w;
    }
    float av[4] = {acc.x, acc.y, acc.z, acc.w};
#pragma unroll
    for (int k = 0; k < 4; ++k) {
        int i = i4 + k;
        float val = av[k] + ((i >= INPUT_SIZE) ? bias[i - INPUT_SIZE] : 0.0f);
        float nv  = (i < N_NEURONS - OUTPUT_SIZE) ? tanhf(val) : val;
        v[i] = nv;
        if (write_out && i >= N_NEURONS - OUTPUT_SIZE)
            out[i - (N_NEURONS - OUTPUT_SIZE)] = val;
    }
}

extern "C" void kernel_launch(void* const* d_in, const int* in_sizes, int n_in,
                              void* d_out, int out_size, void* d_ws, size_t ws_size,
                              hipStream_t stream) {
    const float* x    = (const float*)d_in[0];
    const float* w    = (const float*)d_in[1];
    const float* bias = (const float*)d_in[2];
    const int*   src  = (const int*)d_in[3];
    const int*   dst  = (const int*)d_in[4];
    float* out = (float*)d_out;

    const int blk = 256;
    const int grid_n   = (N_NEURONS + blk - 1) / blk;
    const int red_grid = (N_NEURONS / 4 + blk - 1) / blk;

    // sorted-path ws layout: v | partials | p2 | recs | gcur
    float* v        = (float*)d_ws;
    float* partials = v + N_NEURONS;
    float* p2       = partials + (size_t)RANGES * CBLK * BIN;
    int2*  recs     = (int2*)(p2 + (size_t)RG * N_NEURONS);
    int*   gcur     = (int*)(recs + (size_t)RANGES * CAP);
    size_t need = (size_t)((char*)(gcur + RANGES) - (char*)d_ws);

    if (ws_size >= need) {
        init_all<<<grid_n, blk, 0, stream>>>(x, v, gcur);
        reorder_partition<<<B_CNT, RB_BLK, 0, stream>>>(w, src, dst, recs, gcur);
        for (int s = 0; s < STEPS; ++s) {
            scatter_sorted<<<RANGES * CBLK, SCAT_BLK, 0, stream>>>(
                recs, gcur, v, partials);
            reduce_stage1<<<dim3(red_grid, RG), blk, 0, stream>>>(partials, p2);
            reduce_stage2<<<red_grid, blk, 0, stream>>>(
                p2, bias, v, out, s == STEPS - 1 ? 1 : 0);
        }
    } else {
        long C = (long)(ws_size / 4 / N_NEURONS) - 1;
        if (C > 64) C = 64;
        if (C < 1) C = 1;
        float* part_fb = v + N_NEURONS;
        init_state_fb<<<grid_n, blk, 0, stream>>>(x, v);
        for (int s = 0; s < STEPS; ++s) {
            scatter_binned<<<RANGES * (int)C, SCAT_BLK, 0, stream>>>(
                w, src, dst, v, part_fb, (int)C);
            reduce_update_fb<<<red_grid, blk, 0, stream>>>(
                part_fb, bias, v, out, (int)C, s == STEPS - 1 ? 1 : 0);
        }
    }
}